// Round 11
// baseline (188.640 us; speedup 1.0000x reference)
//
#include <hip/hip_runtime.h>

typedef __attribute__((ext_vector_type(2))) float f32x2;
typedef __attribute__((ext_vector_type(4))) float f32x4;
typedef __attribute__((ext_vector_type(8))) short s16x8;
typedef __attribute__((ext_vector_type(4))) unsigned short u16x4;

#define NH 16
#define SEQ 2048
#define WIDTH 3072
#define DH 64
#define KVB 64
#define NT (SEQ / KVB)
#define QSCALE 0.125f  /* scale^2 folded into Q */
#define SHIFT 8.0f     /* folded into MFMA C-init; p = e^(s-8), exact after final divide */

__device__ __forceinline__ unsigned short f2bf(float f) {
  union { __bf16 b; unsigned short u; } cv;
  cv.b = (__bf16)f;  // compiler fuses adjacent pairs into v_cvt_pk_bf16_f32
  return cv.u;
}

// 8 waves: wid&3 = q-group (32 rows), wid>>2 = key-half (32 keys of each 64-key tile)
__global__ __launch_bounds__(512, 4) void attn_fwd(const float* __restrict__ qkv,
                                                   float* __restrict__ out) {
  // XCD-bijective swizzle: 512 blocks, 64 consecutive per XCD (head K/V stays L2-local)
  int bid0 = (int)blockIdx.x;
  int bid = (bid0 & 7) * 64 + (bid0 >> 3);
  const int qb = bid & 15;
  const int h  = (bid >> 4) & 15;
  const int b  = bid >> 8;

  const int tid  = (int)threadIdx.x;
  const int lane = tid & 63;
  const int wid  = tid >> 6;
  const int qg   = wid & 3;
  const int kh   = wid >> 2;
  const int col  = lane & 15;
  const int hi   = lane >> 4;
  const int cx   = (col & 7) << 3;   // read-side XOR swizzle (elem units)

  // K tile at [0..4095], Vt tile at [4096..8191] (per buffer); whole array re-used as merge buf.
  __shared__ __align__(16) unsigned short sAll[2][(KVB + DH) * 64];
  __shared__ float lbuf[4 * 2 * 16];

  const size_t base = (size_t)b * SEQ * WIDTH + (size_t)h * (3 * DH);
  const int q0 = qb * 128 + qg * 32;

  // ---- Q B-frags (QSCALE folded): n=q=col, k=32c+8hi+j ----
  s16x8 qf[2][2];
#pragma unroll
  for (int rb = 0; rb < 2; ++rb) {
    const float* qp = qkv + base + (size_t)(q0 + rb * 16 + col) * WIDTH;
#pragma unroll
    for (int c = 0; c < 2; ++c) {
      const f32x4 f0 = *(const f32x4*)(qp + 32 * c + 8 * hi);
      const f32x4 f1 = *(const f32x4*)(qp + 32 * c + 8 * hi + 4);
      s16x8 v;
#pragma unroll
      for (int j = 0; j < 4; ++j) {
        v[j]     = (short)f2bf(f0[j] * QSCALE);
        v[4 + j] = (short)f2bf(f1[j] * QSCALE);
      }
      qf[rb][c] = v;
    }
  }

  f32x4 oacc[2][4];
  float l_[2] = {0.0f, 0.0f};
#pragma unroll
  for (int rb = 0; rb < 2; ++rb)
#pragma unroll
    for (int nc = 0; nc < 4; ++nc)
#pragma unroll
      for (int r = 0; r < 4; ++r) oacc[rb][nc][r] = 0.0f;

  // staging decomposition (512 threads, one 64-key tile per block)
  const int krow = tid >> 3;                                   // K: 1 row x 8 floats
  const int kdc8 = (tid & 7) * 8;
  const int vdg = tid & 31, vkg = tid >> 5;                    // V: 4 keys x 2 d
  // permuted key position: key 4*vkg+t -> pos pbase+t (PA slot order, inverse mapping)
  const int pbase = 32 * (vkg >> 3) + 8 * (vkg & 3) + 4 * ((vkg >> 2) & 1);

  f32x4 kr[2];
  f32x2 vr[4];

  auto load_tile = [&](int t) {
    const float* kg = qkv + base + (size_t)(t * KVB + krow) * WIDTH + DH + kdc8;
    kr[0] = *(const f32x4*)kg;
    kr[1] = *(const f32x4*)(kg + 4);
    const float* vg = qkv + base + (size_t)(t * KVB + vkg * 4) * WIDTH + 2 * DH + vdg * 2;
#pragma unroll
    for (int rr = 0; rr < 4; ++rr) vr[rr] = *(const f32x2*)(vg + (size_t)rr * WIDTH);
  };

  auto write_tile = [&](int pb) {
    {  // K: 1 x b128 at the bank floor
      s16x8 w;
#pragma unroll
      for (int j = 0; j < 4; ++j) {
        w[j]     = (short)f2bf(kr[0][j]);
        w[4 + j] = (short)f2bf(kr[1][j]);
      }
      const int e = (krow * 64 + kdc8) ^ ((krow & 7) << 3);
      *(s16x8*)&sAll[pb][e] = w;
    }
#pragma unroll
    for (int dd = 0; dd < 2; ++dd) {  // Vt: 2 x b64 at permuted positions
      const int d = vdg * 2 + dd;
      u16x4 w;
#pragma unroll
      for (int rr = 0; rr < 4; ++rr) w[rr] = f2bf(vr[rr][dd]);
      const int e = (d * 64 + pbase) ^ ((d & 7) << 3);
      *(u16x4*)&sAll[pb][4096 + e] = w;
    }
  };

  load_tile(0);
  write_tile(0);

  for (int t = 0; t < NT; ++t) {
    const int pb = t & 1;
    __syncthreads();                     // one barrier/tile (dbuf-safe)
    if (t + 1 < NT) load_tile(t + 1);    // global->regs in flight under compute

    // K A-frags (this half's 32 keys): m=key=32kh+16g+col, k=32c+8hi+j
    s16x8 kf[2][2];
#pragma unroll
    for (int g = 0; g < 2; ++g)
#pragma unroll
      for (int c = 0; c < 2; ++c)
        kf[g][c] = *(const s16x8*)&sAll[pb][((32 * kh + 16 * g + col) * 64 + 32 * c + 8 * hi) ^ cx];

    // V B-frags (this half's 32 key-slots): one b128 each
    s16x8 vf[4];
#pragma unroll
    for (int nc = 0; nc < 4; ++nc)
      vf[nc] = *(const s16x8*)&sAll[pb][4096 + (((16 * nc + col) * 64 + 32 * kh + 8 * hi) ^ cx)];

#pragma unroll
    for (int rb = 0; rb < 2; ++rb) {
      // swapped QK^T: S[key=16g+4hi+r (local)][q=col], C pre-initialized to -SHIFT
      f32x4 sa[2];
#pragma unroll
      for (int g = 0; g < 2; ++g)
#pragma unroll
        for (int r = 0; r < 4; ++r) sa[g][r] = -SHIFT;
      __builtin_amdgcn_s_setprio(1);
#pragma unroll
      for (int g = 0; g < 2; ++g)
#pragma unroll
        for (int c = 0; c < 2; ++c)
          sa[g] = __builtin_amdgcn_mfma_f32_16x16x32_bf16(kf[g][c], qf[rb][c], sa[g], 0, 0, 0);
      __builtin_amdgcn_s_setprio(0);

      // fixed-shift softmax: one __expf per score (shift already in C)
      float pr[8];
#pragma unroll
      for (int g = 0; g < 2; ++g)
#pragma unroll
        for (int r = 0; r < 4; ++r) pr[g * 4 + r] = __expf(sa[g][r]);
      l_[rb] += ((pr[0] + pr[1]) + (pr[2] + pr[3])) + ((pr[4] + pr[5]) + (pr[6] + pr[7]));

      // PA A-frag: slot j -> pr[j]  (j>>2 = g, j&3 = r; matches V store permutation)
      s16x8 pa;
#pragma unroll
      for (int j = 0; j < 8; ++j) pa[j] = (short)f2bf(pr[j]);

      __builtin_amdgcn_s_setprio(1);
#pragma unroll
      for (int nc = 0; nc < 4; ++nc)
        oacc[rb][nc] = __builtin_amdgcn_mfma_f32_16x16x32_bf16(pa, vf[nc], oacc[rb][nc], 0, 0, 0);
      __builtin_amdgcn_s_setprio(0);
    }

    if (t + 1 < NT) write_tile((t + 1) & 1);
  }

  // ---- merge key-halves via LDS, then normalize + store (kh==0 waves) ----
  __syncthreads();  // all compute done; safe to re-use sAll as fp32 merge buffer
  float* mbuf = (float*)&sAll[0][0];  // 8192 floats = 4 q-groups x 32 rows x 64 d

  float lred[2];
#pragma unroll
  for (int rb = 0; rb < 2; ++rb) {
    float lv = l_[rb];
    lv += __shfl_xor(lv, 16);
    lv += __shfl_xor(lv, 32);   // sum over hi-groups: l for q=col (this key-half)
    lred[rb] = lv;
  }

  if (kh == 1) {
#pragma unroll
    for (int rb = 0; rb < 2; ++rb) {
#pragma unroll
      for (int nc = 0; nc < 4; ++nc)
#pragma unroll
        for (int r = 0; r < 4; ++r)
          mbuf[qg * 2048 + (rb * 16 + 4 * hi + r) * 64 + nc * 16 + col] = oacc[rb][nc][r];
      if (hi == 0) lbuf[qg * 32 + rb * 16 + col] = lred[rb];
    }
  }
  __syncthreads();
  if (kh == 0) {
#pragma unroll
    for (int rb = 0; rb < 2; ++rb) {
      const float lt_all = lred[rb] + lbuf[qg * 32 + rb * 16 + col];  // total l for q=col
#pragma unroll
      for (int r = 0; r < 4; ++r) {
        const float lt = __shfl(lt_all, 4 * hi + r);   // l for this lane's output row
        const float inv = 1.0f / lt;
        const int q = q0 + rb * 16 + 4 * hi + r;
        float* op = out + ((size_t)b * SEQ + q) * (NH * DH) + h * DH;
#pragma unroll
        for (int nc = 0; nc < 4; ++nc) {
          const float o = oacc[rb][nc][r] +
                          mbuf[qg * 2048 + (rb * 16 + 4 * hi + r) * 64 + nc * 16 + col];
          op[nc * 16 + col] = o * inv;
        }
      }
    }
  }
}

extern "C" void kernel_launch(void* const* d_in, const int* in_sizes, int n_in,
                              void* d_out, int out_size, void* d_ws, size_t ws_size,
                              hipStream_t stream) {
  const float* qkv = (const float*)d_in[0];
  float* out = (float*)d_out;
  (void)in_sizes; (void)n_in; (void)out_size; (void)d_ws; (void)ws_size;
  attn_fwd<<<dim3(512), dim3(512), 0, stream>>>(qkv, out);
}